// Round 1
// baseline (984.845 us; speedup 1.0000x reference)
//
#include <hip/hip_runtime.h>
#include <hip/hip_bf16.h>

// B=8192, L=200, K=9 -> S=81, CENTER=40, DK=DV=128, H=4 (dk=dv=32)
//
// Algebra: scores[h][s] = (q_h . Wk_h xs_s)/sqrt(128) = u_h . xs_s with
//   u_h = q_h^T Wk_h  (bk drops out exactly: softmax shift-invariance).
// surround_d = Wv[d] . y_{h(d)} + bv[d], y_h = sum_s attn[h,s] xs_s
//   (softmax weights sum to 1 so bv folds out of the weighted sum).
// central_d = Wv[d] . xc + bv[d], xc[l] = x[b,l,40].
// Total ~460 KFLOP/batch -> memory-bound: 530 MB of x @ 6.3 TB/s ~ 84 us.

typedef __attribute__((ext_vector_type(8))) short short8;   // 8 bf16
typedef __attribute__((ext_vector_type(4))) float floatx4;

#define MASK_VAL -1000000.0f
#define SCALE 0.08838834764831845f  // 1/sqrt(128)

__device__ __forceinline__ float bf2f(unsigned short v) {
  return __uint_as_float(((unsigned int)v) << 16);
}
__device__ __forceinline__ unsigned short f2bf(float f) {  // RNE
  unsigned int u = __float_as_uint(f);
  u += 0x7fffu + ((u >> 16) & 1u);
  return (unsigned short)(u >> 16);
}

__global__ __launch_bounds__(256, 3)
void fused_attn_kernel(const float* __restrict__ x,
                       const float* __restrict__ Wk,
                       const float* __restrict__ Wv, const float* __restrict__ bv,
                       const float* __restrict__ Wq, const float* __restrict__ bq,
                       const float* __restrict__ Wg, const float* __restrict__ bg,
                       float* __restrict__ out) {
  // LDS budget ~50.6 KB -> 3 WGs/CU.
  __shared__ __align__(16) unsigned short x_nat[200 * 88]; // x[b] bf16, l-major, s-contig (stride 88)
  __shared__ __align__(16) float xc[200];                  // x[b][l][40] fp32
  __shared__ __align__(16) float q_lds[128];
  __shared__ __align__(16) float u_l[200 * 4];             // u[l][h], h-contig for b128 broadcast
  __shared__ __align__(16) float part[4 * 21 * 16];        // scores partials [lr][sq][e][h]
  __shared__ __align__(16) float scores[4 * 97];           // [h][s], stride 97 (bank pad)
  __shared__ __align__(16) unsigned short attn[4 * 96];    // bf16 [h][s], stride 96 (16B rows)
  __shared__ __align__(16) float y_t[4 * 200];             // y[h][l] fp32
  __shared__ float red[2];

  const int tid = threadIdx.x;
  const int b = blockIdx.x;
  const float* __restrict__ xb = x + (size_t)b * 16200;

  // ---- Phase 1: stage x[b] -> bf16 LDS (natural layout) + fp32 center column.
  // Scalar b32 global loads: rows are 324 B so float4 would be misaligned.
  for (int f = tid; f < 16200; f += 256) {
    int l = f / 81;            // compiler emits magic-mul
    int s = f - l * 81;
    float v = xb[f];
    x_nat[l * 88 + s] = f2bf(v);
    if (s == 40) xc[l] = v;
  }
  __syncthreads();

  // ---- Phase 2: q[d] = Wq[d,:].xc + bq[d]
  if (tid < 128) {
    const float* wrow = Wq + tid * 200;
    float acc = 0.f;
#pragma unroll 5
    for (int lq = 0; lq < 50; ++lq) {
      float4 w = ((const float4*)wrow)[lq];
      float4 c = ((const float4*)xc)[lq];
      acc += w.x * c.x + w.y * c.y + w.z * c.z + w.w * c.w;
    }
    q_lds[tid] = acc + bq[tid];
  }
  __syncthreads();

  // ---- Phase 3: u[l][h] = sum_{j<32} q[h*32+j] * Wk[h*32+j][l]
  // Wk column reads: lanes = consecutive l -> coalesced.
  if (tid < 200) {
    float ua[4];
#pragma unroll
    for (int h = 0; h < 4; ++h) {
      float a = 0.f;
#pragma unroll 2
      for (int d4 = h * 8; d4 < h * 8 + 8; ++d4) {
        float4 qv = *(const float4*)&q_lds[d4 * 4];
        const float* wc = Wk + (d4 * 4) * 200 + tid;
        a += qv.x * wc[0] + qv.y * wc[200] + qv.z * wc[400] + qv.w * wc[600];
      }
      ua[h] = a;
    }
    *(float4*)&u_l[tid * 4] = make_float4(ua[0], ua[1], ua[2], ua[3]);
  }
  __syncthreads();

  // ---- Phase 4: scores partials. Thread (lr in 0..3, sq in 0..20):
  // 4 s-values (sq*4+e) x 4 heads over l-range [lr*50, lr*50+50).
  if (tid < 84) {
    int lr = tid / 21;
    int sq = tid - lr * 21;
    float ps[16];
#pragma unroll
    for (int i = 0; i < 16; ++i) ps[i] = 0.f;
    const int lbase = lr * 50;
    for (int i = 0; i < 50; ++i) {
      int l = lbase + i;
      float4 u4 = *(const float4*)&u_l[l * 4];                          // broadcast-ish
      unsigned long long xx = *(const unsigned long long*)&x_nat[l * 88 + sq * 4];
      float x0 = bf2f((unsigned short)(xx));
      float x1 = bf2f((unsigned short)(xx >> 16));
      float x2 = bf2f((unsigned short)(xx >> 32));
      float x3 = bf2f((unsigned short)(xx >> 48));
      ps[0]  += x0 * u4.x; ps[1]  += x0 * u4.y; ps[2]  += x0 * u4.z; ps[3]  += x0 * u4.w;
      ps[4]  += x1 * u4.x; ps[5]  += x1 * u4.y; ps[6]  += x1 * u4.z; ps[7]  += x1 * u4.w;
      ps[8]  += x2 * u4.x; ps[9]  += x2 * u4.y; ps[10] += x2 * u4.z; ps[11] += x2 * u4.w;
      ps[12] += x3 * u4.x; ps[13] += x3 * u4.y; ps[14] += x3 * u4.z; ps[15] += x3 * u4.w;
    }
    float* pb = &part[(lr * 21 + sq) * 16];
#pragma unroll
    for (int e = 0; e < 4; ++e)
      *(float4*)&pb[e * 4] = make_float4(ps[e*4+0], ps[e*4+1], ps[e*4+2], ps[e*4+3]);
  }
  __syncthreads();

  // ---- Phase 5: reduce over the 4 l-ranges -> scores[h][s] (scaled).
  for (int idx = tid; idx < 324; idx += 256) {
    int h = idx & 3, s = idx >> 2;
    int sq = s >> 2, e = s & 3;
    float a = 0.f;
#pragma unroll
    for (int lr = 0; lr < 4; ++lr) a += part[(lr * 21 + sq) * 16 + e * 4 + h];
    scores[h * 97 + s] = a * SCALE;
  }
  __syncthreads();

  // ---- Phase 6: softmax per head (wave w = head w). 81 values: lane + (lane<17 ? lane+64).
  {
    int wid = tid >> 6, lane = tid & 63;
    float v1 = scores[wid * 97 + lane];
    if (lane == 40) v1 += MASK_VAL;              // exp(-1e6) == 0 exactly, matches ref
    bool have2 = lane < 17;
    float v2 = have2 ? scores[wid * 97 + 64 + lane] : -3.0e38f;
    float mx = fmaxf(v1, v2);
#pragma unroll
    for (int o = 32; o >= 1; o >>= 1) mx = fmaxf(mx, __shfl_xor(mx, o, 64));
    float p1 = expf(v1 - mx);
    float p2 = have2 ? expf(v2 - mx) : 0.f;
    float sm = p1 + p2;
#pragma unroll
    for (int o = 32; o >= 1; o >>= 1) sm += __shfl_xor(sm, o, 64);
    float inv = 1.0f / sm;
    attn[wid * 96 + lane] = f2bf(p1 * inv);
    if (have2) attn[wid * 96 + 64 + lane] = f2bf(p2 * inv);
  }
  __syncthreads();

  // ---- Phase 7: y[h][l] = sum_s attn[h][s] * x[l][s] via mfma_f32_16x16x32_bf16.
  // D[m=h][n=l] = A[m][k=s] B[k=s][n=l]; B-frag reads x_nat rows (k=s contiguous).
  // K: 81 -> 3 steps of 32, tail reg-masked (both frags, avoids 0*NaN).
  // N: 200 -> 13 tiles of 16, row index clamped; garbage D cols not written.
  {
    int wid = tid >> 6, lane = tid & 63;
    int g = lane >> 4, m16 = lane & 15;
    int hm = (m16 < 4) ? m16 : 0;               // clamp invalid A rows to row 0
    for (int tile = wid; tile < 13; tile += 4) {
      floatx4 acc = {0.f, 0.f, 0.f, 0.f};
      int n = tile * 16 + m16;
      int lc = (n < 200) ? n : 199;
#pragma unroll
      for (int ks = 0; ks < 3; ++ks) {
        int k0 = ks * 32 + g * 8;
        short8 a8 = *(const short8*)&attn[hm * 96 + k0];
        short8 b8 = *(const short8*)&x_nat[lc * 88 + k0];
        if (ks == 2) {
#pragma unroll
          for (int j = 0; j < 8; ++j)
            if (k0 + j > 80) { a8[j] = 0; b8[j] = 0; }
        }
        acc = __builtin_amdgcn_mfma_f32_16x16x32_bf16(a8, b8, acc, 0, 0, 0);
      }
      // C layout: col = lane&15 (=n), row = (lane>>4)*4 + reg (=h). Valid h rows live in g==0.
      if (g == 0 && n < 200) {
#pragma unroll
        for (int r = 0; r < 4; ++r) y_t[r * 200 + n] = acc[r];
      }
    }
  }
  __syncthreads();

  // ---- Phase 8: central/surround/gate/output. Thread d in [0,128).
  float central_v = 0.f, surround_v = 0.f;
  if (tid < 128) {
    int h = tid >> 5;
    const float* wrow = Wv + tid * 200;
    float ac = 0.f, as = 0.f;
#pragma unroll 5
    for (int lq = 0; lq < 50; ++lq) {
      float4 w  = ((const float4*)wrow)[lq];
      float4 c  = ((const float4*)xc)[lq];
      float4 yv = *(const float4*)&y_t[h * 200 + lq * 4];
      ac += w.x * c.x + w.y * c.y + w.z * c.z + w.w * c.w;
      as += w.x * yv.x + w.y * yv.y + w.z * yv.z + w.w * yv.w;
    }
    float bvv = bv[tid];
    central_v = ac + bvv;
    surround_v = as + bvv;
    float diff = (ac - as) * Wg[tid];            // bv cancels in (central - surround)
#pragma unroll
    for (int o = 32; o >= 1; o >>= 1) diff += __shfl_xor(diff, o, 64);
    if ((tid & 63) == 0) red[tid >> 6] = diff;
  }
  __syncthreads();
  if (tid < 128) {
    float z = red[0] + red[1] + bg[0];
    float gate = 1.0f / (1.0f + expf(-z));
    out[(size_t)b * 128 + tid] = central_v + gate * surround_v;
  }
}

extern "C" void kernel_launch(void* const* d_in, const int* in_sizes, int n_in,
                              void* d_out, int out_size, void* d_ws, size_t ws_size,
                              hipStream_t stream) {
  const float* x  = (const float*)d_in[0];
  const float* Wk = (const float*)d_in[1];
  // d_in[2] = bk: provably a no-op (per-head constant shift of scores; softmax invariant)
  const float* Wv = (const float*)d_in[3];
  const float* bv = (const float*)d_in[4];
  const float* Wq = (const float*)d_in[5];
  const float* bq = (const float*)d_in[6];
  const float* Wg = (const float*)d_in[7];
  const float* bg = (const float*)d_in[8];
  float* out = (float*)d_out;

  hipLaunchKernelGGL(fused_attn_kernel, dim3(8192), dim3(256), 0, stream,
                     x, Wk, Wv, bv, Wq, bq, Wg, bg, out);
}

// Round 2
// 816.481 us; speedup vs baseline: 1.2062x; 1.2062x over previous
//
#include <hip/hip_runtime.h>
#include <hip/hip_bf16.h>

// B=8192, L=200, K=9 -> S=81, CENTER=40, DK=DV=128, H=4 (dk=dv=32)
//
// Algebra: scores[h][s] = u_h . xs_s with u_h = q_h^T Wk_h (bk drops out:
// softmax shift-invariance). surround_d = Wv[d].y_h + bv[d],
// y_h = sum_s attn[h,s] xs_s (softmax weights sum to 1 -> bv folds out).
// central_d = Wv[d].xc + bv[d], xc[l] = x[b,l,40].
// Memory floor: x = 530 MB @ 6.3 TB/s ~ 84 us (less if L3-resident half).
//
// R2 changes vs R1 (465 us, HBM 7.5%, all pipes idle -> latency-bound):
//  - Phase 1: 16x float4 loads batched into registers BEFORE any ds_write
//    (R1's load->convert->store per-iter loop had ~1 load in flight/wave).
//  - Wq/Wv pre-transposed into d_ws ([l4][d] float4-interleaved) by a tiny
//    prep kernel -> Phase 2/8 global reads fully coalesced (R1: 64 lanes x
//    800B-apart 16B scatters per instruction).

typedef __attribute__((ext_vector_type(8))) short short8;   // 8 bf16
typedef __attribute__((ext_vector_type(4))) float floatx4;

#define MASK_VAL -1000000.0f
#define SCALE 0.08838834764831845f  // 1/sqrt(128)

__device__ __forceinline__ float bf2f(unsigned short v) {
  return __uint_as_float(((unsigned int)v) << 16);
}
__device__ __forceinline__ unsigned short f2bf(float f) {  // RNE
  unsigned int u = __float_as_uint(f);
  u += 0x7fffu + ((u >> 16) & 1u);
  return (unsigned short)(u >> 16);
}

// Transpose Wq, Wv (128x200) -> [l4][d] float4 blocks (50x128 float4 each)
// so the main kernel's per-d dot products read coalesced b128.
__global__ void prep_weights(const float* __restrict__ Wq,
                             const float* __restrict__ Wv,
                             float4* __restrict__ wq4, float4* __restrict__ wv4) {
  int i = blockIdx.x * 256 + threadIdx.x;
  if (i < 6400) {
    int l4 = i >> 7, d = i & 127;
    const float* rq = Wq + d * 200 + l4 * 4;
    wq4[i] = make_float4(rq[0], rq[1], rq[2], rq[3]);
    const float* rv = Wv + d * 200 + l4 * 4;
    wv4[i] = make_float4(rv[0], rv[1], rv[2], rv[3]);
  }
}

template <bool USE_T4>
__global__ __launch_bounds__(256, 3)
void fused_attn_kernel(const float* __restrict__ x,
                       const float* __restrict__ Wk,
                       const float* __restrict__ Wv, const float* __restrict__ bv,
                       const float* __restrict__ Wq, const float* __restrict__ bq,
                       const float* __restrict__ Wg, const float* __restrict__ bg,
                       const float4* __restrict__ wq4, const float4* __restrict__ wv4,
                       float* __restrict__ out) {
  // LDS ~50.7 KB -> 3 WGs/CU.
  __shared__ __align__(16) unsigned short x_nat[200 * 88]; // x[b] bf16, l-major, s-contig (stride 88; 176B rows keep b128 16B-aligned)
  __shared__ __align__(16) float xc[200];                  // x[b][l][40] fp32
  __shared__ __align__(16) float q_lds[128];
  __shared__ __align__(16) float u_l[200 * 4];             // u[l][h], h-contig
  __shared__ __align__(16) float part[4 * 21 * 16];        // scores partials [lr][sq][e][h]
  __shared__ __align__(16) float scores[4 * 97];           // [h][s], stride 97 (bank pad)
  __shared__ __align__(16) unsigned short attn[4 * 96];    // bf16 [h][s], stride 96 (16B rows)
  __shared__ __align__(16) float y_t[4 * 200];             // y[h][l] fp32
  __shared__ float red[2];

  const int tid = threadIdx.x;
  const int b = blockIdx.x;

  // ---- Phase 1: stage x[b] -> bf16 LDS + fp32 center column.
  // 4050 float4s; issue all 16 loads per thread before any LDS store so the
  // wave keeps ~16 vmem ops in flight (R1 had ~1 -> latency-serialized).
  {
    const float4* __restrict__ x4 = (const float4*)(x + (size_t)b * 16200);
    float4 buf[16];
#pragma unroll
    for (int i = 0; i < 16; ++i) {
      int id = tid + i * 256;                 // i<15 always in range (3839<4050)
      if (id < 4050) buf[i] = x4[id];
    }
#pragma unroll
    for (int i = 0; i < 16; ++i) {
      int id = tid + i * 256;
      if (id < 4050) {
        int f0 = id * 4;
#pragma unroll
        for (int j = 0; j < 4; ++j) {
          int fj = f0 + j;
          int lj = fj / 81;                   // magic-mul
          int sj = fj - lj * 81;
          float v = (j == 0) ? buf[i].x : (j == 1) ? buf[i].y : (j == 2) ? buf[i].z : buf[i].w;
          x_nat[lj * 88 + sj] = f2bf(v);
          if (sj == 40) xc[lj] = v;
        }
      }
    }
  }
  __syncthreads();

  // ---- Phase 2: q[d] = Wq[d,:].xc + bq[d]
  if (tid < 128) {
    float acc = 0.f;
    if (USE_T4) {
#pragma unroll 5
      for (int lq = 0; lq < 50; ++lq) {
        float4 w = wq4[lq * 128 + tid];       // coalesced b128, L2-resident
        float4 c = ((const float4*)xc)[lq];
        acc += w.x * c.x + w.y * c.y + w.z * c.z + w.w * c.w;
      }
    } else {
      const float* wrow = Wq + tid * 200;
#pragma unroll 5
      for (int lq = 0; lq < 50; ++lq) {
        float4 w = ((const float4*)wrow)[lq];
        float4 c = ((const float4*)xc)[lq];
        acc += w.x * c.x + w.y * c.y + w.z * c.z + w.w * c.w;
      }
    }
    q_lds[tid] = acc + bq[tid];
  }
  __syncthreads();

  // ---- Phase 3: u[l][h] = sum_{j<32} q[h*32+j] * Wk[h*32+j][l]
  // Wk column reads: lanes = consecutive l -> coalesced.
  if (tid < 200) {
    float ua[4];
#pragma unroll
    for (int h = 0; h < 4; ++h) {
      float a = 0.f;
#pragma unroll 2
      for (int d4 = h * 8; d4 < h * 8 + 8; ++d4) {
        float4 qv = *(const float4*)&q_lds[d4 * 4];
        const float* wc = Wk + (d4 * 4) * 200 + tid;
        a += qv.x * wc[0] + qv.y * wc[200] + qv.z * wc[400] + qv.w * wc[600];
      }
      ua[h] = a;
    }
    *(float4*)&u_l[tid * 4] = make_float4(ua[0], ua[1], ua[2], ua[3]);
  }
  __syncthreads();

  // ---- Phase 4: scores partials. Thread (lr in 0..3, sq in 0..20):
  // 4 s-values x 4 heads over l-range [lr*50, lr*50+50).
  if (tid < 84) {
    int lr = tid / 21;
    int sq = tid - lr * 21;
    float ps[16];
#pragma unroll
    for (int i = 0; i < 16; ++i) ps[i] = 0.f;
    const int lbase = lr * 50;
    for (int i = 0; i < 50; ++i) {
      int l = lbase + i;
      float4 u4 = *(const float4*)&u_l[l * 4];
      unsigned long long xx = *(const unsigned long long*)&x_nat[l * 88 + sq * 4];
      float x0 = bf2f((unsigned short)(xx));
      float x1 = bf2f((unsigned short)(xx >> 16));
      float x2 = bf2f((unsigned short)(xx >> 32));
      float x3 = bf2f((unsigned short)(xx >> 48));
      ps[0]  += x0 * u4.x; ps[1]  += x0 * u4.y; ps[2]  += x0 * u4.z; ps[3]  += x0 * u4.w;
      ps[4]  += x1 * u4.x; ps[5]  += x1 * u4.y; ps[6]  += x1 * u4.z; ps[7]  += x1 * u4.w;
      ps[8]  += x2 * u4.x; ps[9]  += x2 * u4.y; ps[10] += x2 * u4.z; ps[11] += x2 * u4.w;
      ps[12] += x3 * u4.x; ps[13] += x3 * u4.y; ps[14] += x3 * u4.z; ps[15] += x3 * u4.w;
    }
    float* pb = &part[(lr * 21 + sq) * 16];
#pragma unroll
    for (int e = 0; e < 4; ++e)
      *(float4*)&pb[e * 4] = make_float4(ps[e*4+0], ps[e*4+1], ps[e*4+2], ps[e*4+3]);
  }
  __syncthreads();

  // ---- Phase 5: reduce over the 4 l-ranges -> scores[h][s] (scaled).
  for (int idx = tid; idx < 324; idx += 256) {
    int h = idx & 3, s = idx >> 2;
    int sq = s >> 2, e = s & 3;
    float a = 0.f;
#pragma unroll
    for (int lr = 0; lr < 4; ++lr) a += part[(lr * 21 + sq) * 16 + e * 4 + h];
    scores[h * 97 + s] = a * SCALE;
  }
  __syncthreads();

  // ---- Phase 6: softmax per head (wave w = head w).
  {
    int wid = tid >> 6, lane = tid & 63;
    float v1 = scores[wid * 97 + lane];
    if (lane == 40) v1 += MASK_VAL;              // exp(-1e6)==0 exactly, matches ref
    bool have2 = lane < 17;
    float v2 = have2 ? scores[wid * 97 + 64 + lane] : -3.0e38f;
    float mx = fmaxf(v1, v2);
#pragma unroll
    for (int o = 32; o >= 1; o >>= 1) mx = fmaxf(mx, __shfl_xor(mx, o, 64));
    float p1 = expf(v1 - mx);
    float p2 = have2 ? expf(v2 - mx) : 0.f;
    float sm = p1 + p2;
#pragma unroll
    for (int o = 32; o >= 1; o >>= 1) sm += __shfl_xor(sm, o, 64);
    float inv = 1.0f / sm;
    attn[wid * 96 + lane] = f2bf(p1 * inv);
    if (have2) attn[wid * 96 + 64 + lane] = f2bf(p2 * inv);
  }
  __syncthreads();

  // ---- Phase 7: y[h][l] = sum_s attn[h][s] * x[l][s] via mfma_f32_16x16x32_bf16.
  // D[m=h][n=l]; B-frag reads x_nat rows (k=s contiguous). K 81->3x32 tail
  // reg-masked (both frags). N 200 -> 13 tiles of 16, row clamped.
  {
    int wid = tid >> 6, lane = tid & 63;
    int g = lane >> 4, m16 = lane & 15;
    int hm = (m16 < 4) ? m16 : 0;
    for (int tile = wid; tile < 13; tile += 4) {
      floatx4 acc = {0.f, 0.f, 0.f, 0.f};
      int n = tile * 16 + m16;
      int lc = (n < 200) ? n : 199;
#pragma unroll
      for (int ks = 0; ks < 3; ++ks) {
        int k0 = ks * 32 + g * 8;
        short8 a8 = *(const short8*)&attn[hm * 96 + k0];
        short8 b8 = *(const short8*)&x_nat[lc * 88 + k0];
        if (ks == 2) {
#pragma unroll
          for (int j = 0; j < 8; ++j)
            if (k0 + j > 80) { a8[j] = 0; b8[j] = 0; }
        }
        acc = __builtin_amdgcn_mfma_f32_16x16x32_bf16(a8, b8, acc, 0, 0, 0);
      }
      // C layout: col=lane&15 (=n), row=(lane>>4)*4+reg (=h); valid h in g==0.
      if (g == 0 && n < 200) {
#pragma unroll
        for (int r = 0; r < 4; ++r) y_t[r * 200 + n] = acc[r];
      }
    }
  }
  __syncthreads();

  // ---- Phase 8: central/surround/gate/output. Thread d in [0,128).
  float central_v = 0.f, surround_v = 0.f;
  if (tid < 128) {
    int h = tid >> 5;
    float ac = 0.f, as = 0.f;
    if (USE_T4) {
#pragma unroll 5
      for (int lq = 0; lq < 50; ++lq) {
        float4 w  = wv4[lq * 128 + tid];          // coalesced b128, L2-resident
        float4 c  = ((const float4*)xc)[lq];
        float4 yv = *(const float4*)&y_t[h * 200 + lq * 4];
        ac += w.x * c.x + w.y * c.y + w.z * c.z + w.w * c.w;
        as += w.x * yv.x + w.y * yv.y + w.z * yv.z + w.w * yv.w;
      }
    } else {
      const float* wrow = Wv + tid * 200;
#pragma unroll 5
      for (int lq = 0; lq < 50; ++lq) {
        float4 w  = ((const float4*)wrow)[lq];
        float4 c  = ((const float4*)xc)[lq];
        float4 yv = *(const float4*)&y_t[h * 200 + lq * 4];
        ac += w.x * c.x + w.y * c.y + w.z * c.z + w.w * c.w;
        as += w.x * yv.x + w.y * yv.y + w.z * yv.z + w.w * yv.w;
      }
    }
    float bvv = bv[tid];
    central_v = ac + bvv;
    surround_v = as + bvv;
    float diff = (ac - as) * Wg[tid];            // bv cancels in (central - surround)
#pragma unroll
    for (int o = 32; o >= 1; o >>= 1) diff += __shfl_xor(diff, o, 64);
    if ((tid & 63) == 0) red[tid >> 6] = diff;
  }
  __syncthreads();
  if (tid < 128) {
    float z = red[0] + red[1] + bg[0];
    float gate = 1.0f / (1.0f + expf(-z));
    out[(size_t)b * 128 + tid] = central_v + gate * surround_v;
  }
}

extern "C" void kernel_launch(void* const* d_in, const int* in_sizes, int n_in,
                              void* d_out, int out_size, void* d_ws, size_t ws_size,
                              hipStream_t stream) {
  const float* x  = (const float*)d_in[0];
  const float* Wk = (const float*)d_in[1];
  // d_in[2] = bk: provably a no-op (per-head constant score shift; softmax-invariant)
  const float* Wv = (const float*)d_in[3];
  const float* bv = (const float*)d_in[4];
  const float* Wq = (const float*)d_in[5];
  const float* bq = (const float*)d_in[6];
  const float* Wg = (const float*)d_in[7];
  const float* bg = (const float*)d_in[8];
  float* out = (float*)d_out;

  const size_t need = 2 * 6400 * sizeof(float4);  // 204.8 KB
  if (ws_size >= need) {
    float4* wq4 = (float4*)d_ws;
    float4* wv4 = wq4 + 6400;
    hipLaunchKernelGGL(prep_weights, dim3(25), dim3(256), 0, stream, Wq, Wv, wq4, wv4);
    hipLaunchKernelGGL(fused_attn_kernel<true>, dim3(8192), dim3(256), 0, stream,
                       x, Wk, Wv, bv, Wq, bq, Wg, bg, wq4, wv4, out);
  } else {
    hipLaunchKernelGGL(fused_attn_kernel<false>, dim3(8192), dim3(256), 0, stream,
                       x, Wk, Wv, bv, Wq, bq, Wg, bg, (const float4*)nullptr,
                       (const float4*)nullptr, out);
  }
}